// Round 1
// baseline (166.136 us; speedup 1.0000x reference)
//
#include <hip/hip_runtime.h>
#include <math.h>

#define BB 32
#define TT 2048
#define CC 128
#define EE 256
#define LL 512
#define TYY 128
#define PP 24

// ws layout (floats):
//   gsum : [B][P][C]  at 0        (98304)
//   gcnt : [B][P][C]  at 98304    (98304)
//   sinp : [B][E]     at 196608   (8192)
//   Y    : [B][C]     at 204800   (4096)
#define WS_SUM  0
#define WS_CNT  98304
#define WS_SINP 196608
#define WS_Y    204800
#define WS_ZERO_N 204800   // floats to zero each call

__global__ __launch_bounds__(256) void k_zero(float* ws, int n) {
    int i = blockIdx.x * 256 + threadIdx.x;
    int stride = gridDim.x * 256;
    for (; i < n; i += stride) ws[i] = 0.0f;
}

// Phase-bucket masked sum & count.
// grid = B * 8 (t-chunks of 256), block = 256 threads (2 t-subgroups x 128 c)
__global__ __launch_bounds__(256) void k_cycle(const float* __restrict__ ts,
                                               const float* __restrict__ X,
                                               const int*   __restrict__ M,
                                               float* __restrict__ gsum,
                                               float* __restrict__ gcnt) {
    __shared__ float s_sum[PP * CC];
    __shared__ float s_cnt[PP * CC];
    const int tid = threadIdx.x;
    for (int i = tid; i < PP * CC; i += 256) { s_sum[i] = 0.0f; s_cnt[i] = 0.0f; }
    __syncthreads();

    const int blk = blockIdx.x;
    const int b = blk >> 3;
    const int chunk = blk & 7;
    const int c = tid & 127;
    const int tg = tid >> 7;            // 0 or 1
    const int tbase = chunk * 256;

    for (int i = 0; i < 128; ++i) {
        const int t = tbase + i * 2 + tg;
        const float tsv = ts[b * TT + t];
        int p = ((int)floorf(tsv)) % PP; if (p < 0) p += PP;
        const long idx = ((long)(b * TT + t)) * CC + c;
        const float m = (float)M[idx];
        const float x = X[idx];
        atomicAdd(&s_sum[p * CC + c], x * m);
        atomicAdd(&s_cnt[p * CC + c], m);
    }
    __syncthreads();
    float* gs = gsum + b * PP * CC;
    float* gc = gcnt + b * PP * CC;
    for (int i = tid; i < PP * CC; i += 256) {
        atomicAdd(&gs[i], s_sum[i]);
        atomicAdd(&gc[i], s_cnt[i]);
    }
}

// sin-pool: accumulate sum_t (v + sin(v)), v = ts*w[e]+b[e]
// grid = B * 8 (t-chunks of 256), block = 256 threads (e)
__global__ __launch_bounds__(256) void k_time(const float* __restrict__ ts,
                                              const float* __restrict__ tw,
                                              const float* __restrict__ tb,
                                              float* __restrict__ sinp) {
    __shared__ float s_ts[256];
    const int tid = threadIdx.x;
    const int blk = blockIdx.x;
    const int b = blk >> 3;
    const int chunk = blk & 7;
    s_ts[tid] = ts[b * TT + chunk * 256 + tid];
    __syncthreads();
    const float w = tw[tid];
    const float bb = tb[tid];
    float acc = 0.0f;
#pragma unroll 8
    for (int j = 0; j < 256; ++j) {
        const float v = fmaf(s_ts[j], w, bb);
        acc += v + __sinf(v);
    }
    atomicAdd(&sinp[b * EE + tid], acc);
}

// decoder MLP per batch row. block = 512 threads, grid = B
__global__ __launch_bounds__(512) void k_mlp(const float* __restrict__ sinp,
                                             const float* __restrict__ ce,
                                             const float* __restrict__ w1,
                                             const float* __restrict__ b1,
                                             const float* __restrict__ w2,
                                             const float* __restrict__ b2,
                                             float* __restrict__ Yout) {
    __shared__ float s_pool[EE];
    __shared__ float s_h[LL];
    const int b = blockIdx.x;
    const int tid = threadIdx.x;
    if (tid < EE) {
        float cm = 0.0f;
#pragma unroll 4
        for (int c = 0; c < CC; ++c) cm += ce[c * EE + tid];
        s_pool[tid] = sinp[b * EE + tid] * (1.0f / TT) + cm * (1.0f / CC);
    }
    __syncthreads();
    float hacc = b1[tid];
#pragma unroll 4
    for (int e = 0; e < EE; ++e) hacc = fmaf(s_pool[e], w1[e * LL + tid], hacc);
    s_h[tid] = fmaxf(hacc, 0.0f);
    __syncthreads();
    if (tid < CC) {
        float y = b2[tid];
#pragma unroll 4
        for (int l = 0; l < LL; ++l) y = fmaf(s_h[l], w2[l * CC + tid], y);
        Yout[b * CC + tid] = y;
    }
}

// output: Y + c_base gathered at phase(y_times)
// grid = B*Ty, block = 128 (c)
__global__ __launch_bounds__(128) void k_out(const float* __restrict__ yt,
                                             const float* __restrict__ gsum,
                                             const float* __restrict__ gcnt,
                                             const float* __restrict__ Yv,
                                             float* __restrict__ out) {
    const int blk = blockIdx.x;
    const int b = blk >> 7;
    const int ty = blk & 127;
    const int c = threadIdx.x;
    const float v = yt[b * TYY + ty];
    int p = ((int)floorf(v)) % PP; if (p < 0) p += PP;
    const float s = gsum[(b * PP + p) * CC + c];
    const float n = gcnt[(b * PP + p) * CC + c];
    out[(long)(b * TYY + ty) * CC + c] = Yv[b * CC + c] + s / fmaxf(n, 1.0f);
}

extern "C" void kernel_launch(void* const* d_in, const int* in_sizes, int n_in,
                              void* d_out, int out_size, void* d_ws, size_t ws_size,
                              hipStream_t stream) {
    const float* ts   = (const float*)d_in[0];   // [B,T]
    const float* X    = (const float*)d_in[1];   // [B,T,C]
    const int*   M    = (const int*)  d_in[2];   // [B,T,C]
    const float* yt   = (const float*)d_in[3];   // [B,Ty]
    const float* tw   = (const float*)d_in[4];   // [E]
    const float* tb   = (const float*)d_in[5];   // [E]
    const float* ce   = (const float*)d_in[6];   // [C,E]
    const float* w1   = (const float*)d_in[7];   // [E,L]
    const float* b1   = (const float*)d_in[8];   // [L]
    const float* w2   = (const float*)d_in[9];   // [L,C]
    const float* b2   = (const float*)d_in[10];  // [C]
    float* out = (float*)d_out;

    float* ws = (float*)d_ws;
    float* gsum = ws + WS_SUM;
    float* gcnt = ws + WS_CNT;
    float* sinp = ws + WS_SINP;
    float* Yv   = ws + WS_Y;

    k_zero<<<256, 256, 0, stream>>>(ws, WS_ZERO_N);
    k_cycle<<<BB * 8, 256, 0, stream>>>(ts, X, M, gsum, gcnt);
    k_time<<<BB * 8, 256, 0, stream>>>(ts, tw, tb, sinp);
    k_mlp<<<BB, 512, 0, stream>>>(sinp, ce, w1, b1, w2, b2, Yv);
    k_out<<<BB * TYY, 128, 0, stream>>>(yt, gsum, gcnt, Yv, out);
}

// Round 2
// 122.263 us; speedup vs baseline: 1.3588x; 1.3588x over previous
//
#include <hip/hip_runtime.h>
#include <math.h>

#define BB 32
#define TT 2048
#define CC 128
#define EE 256
#define LL 512
#define TYY 128
#define PP 24

// ws layout (floats):
//   gsum : [B][P][C]  at 0        (98304)
//   gcnt : [B][P][C]  at 98304    (98304)
//   sinp : [B][E]     at 196608   (8192)
//   Y    : [B][C]     at 204800   (4096)
#define WS_SUM  0
#define WS_CNT  98304
#define WS_SINP 196608
#define WS_Y    204800
#define WS_ZERO_N 204800

__global__ __launch_bounds__(256) void k_zero(float* ws, int n) {
    int i = blockIdx.x * 256 + threadIdx.x;
    int stride = gridDim.x * 256;
    for (; i < n; i += stride) ws[i] = 0.0f;
}

// Phase-bucket masked sum & count.
// grid = B*16 (t-chunks of 128), block = 512 (8 waves; each wave owns 16 t's,
// 64 lanes cover C=128 via float2/int2).
__global__ __launch_bounds__(512) void k_cycle(const float* __restrict__ ts,
                                               const float* __restrict__ X,
                                               const int*   __restrict__ M,
                                               float* __restrict__ gsum,
                                               float* __restrict__ gcnt) {
    __shared__ float s_sum[PP * CC];
    __shared__ float s_cnt[PP * CC];
    const int tid = threadIdx.x;
    for (int i = tid; i < PP * CC; i += 512) { s_sum[i] = 0.0f; s_cnt[i] = 0.0f; }
    __syncthreads();

    const int blk = blockIdx.x;
    const int b = blk >> 4;
    const int chunk = blk & 15;
    const int wave = tid >> 6;
    const int lane = tid & 63;
    const int c2 = lane * 2;
    const int tbase = chunk * 128 + wave * 16;

#pragma unroll 4
    for (int i = 0; i < 16; ++i) {
        const int t = tbase + i;
        const float tsv = ts[b * TT + t];           // wave-uniform broadcast
        int p = ((int)floorf(tsv)) % PP;            // ts >= 0
        const long base = ((long)(b * TT + t)) * CC + c2;
        const float2 xv = *(const float2*)(X + base);
        const int2   mv = *(const int2*)(M + base);
        const float m0 = (float)mv.x, m1 = (float)mv.y;
        atomicAdd(&s_sum[p * CC + c2],     xv.x * m0);
        atomicAdd(&s_sum[p * CC + c2 + 1], xv.y * m1);
        atomicAdd(&s_cnt[p * CC + c2],     m0);
        atomicAdd(&s_cnt[p * CC + c2 + 1], m1);
    }
    __syncthreads();
    float* gs = gsum + b * PP * CC;
    float* gc = gcnt + b * PP * CC;
    for (int i = tid; i < PP * CC; i += 512) {
        atomicAdd(&gs[i], s_sum[i]);
        atomicAdd(&gc[i], s_cnt[i]);
    }
}

// sin-pool: accumulate sum_t (v + sin(v)), v = ts*w[e]+b[e]
// grid = B*8 (t-chunks of 256), block = 256 (e)
__global__ __launch_bounds__(256) void k_time(const float* __restrict__ ts,
                                              const float* __restrict__ tw,
                                              const float* __restrict__ tb,
                                              float* __restrict__ sinp) {
    __shared__ float s_ts[256];
    const int tid = threadIdx.x;
    const int blk = blockIdx.x;
    const int b = blk >> 3;
    const int chunk = blk & 7;
    s_ts[tid] = ts[b * TT + chunk * 256 + tid];
    __syncthreads();
    const float w = tw[tid];
    const float bb = tb[tid];
    float acc = 0.0f;
#pragma unroll 16
    for (int j = 0; j < 256; ++j) {
        const float v = fmaf(s_ts[j], w, bb);
        acc += v + __sinf(v);
    }
    atomicAdd(&sinp[b * EE + tid], acc);
}

// decoder MLP per batch row. block = 512 threads, grid = B.
// All 512 threads active in every phase; unroll 16 for load pipelining.
__global__ __launch_bounds__(512) void k_mlp(const float* __restrict__ sinp,
                                             const float* __restrict__ ce,
                                             const float* __restrict__ w1,
                                             const float* __restrict__ b1,
                                             const float* __restrict__ w2,
                                             const float* __restrict__ b2,
                                             float* __restrict__ Yout) {
    __shared__ float s_pool[EE];
    __shared__ float s_h[LL];
    __shared__ float s_part[512];
    const int b = blockIdx.x;
    const int tid = threadIdx.x;

    // cmean: e = tid&255, half = tid>>8 sums 64 c's each
    {
        const int e = tid & 255;
        const int half = tid >> 8;
        float cm = 0.0f;
#pragma unroll 16
        for (int c = half * 64; c < half * 64 + 64; ++c) cm += ce[c * EE + e];
        s_part[tid] = cm;
    }
    __syncthreads();
    if (tid < EE)
        s_pool[tid] = sinp[b * EE + tid] * (1.0f / TT)
                    + (s_part[tid] + s_part[tid + 256]) * (1.0f / CC);
    __syncthreads();

    // h: one l per thread
    float hacc = b1[tid];
#pragma unroll 16
    for (int e = 0; e < EE; ++e) hacc = fmaf(s_pool[e], w1[e * LL + tid], hacc);
    s_h[tid] = fmaxf(hacc, 0.0f);
    __syncthreads();

    // y: c = tid&127, q = tid>>7 over l-quarters
    {
        const int c = tid & 127;
        const int q = tid >> 7;
        float y = 0.0f;
#pragma unroll 16
        for (int l = q * 128; l < q * 128 + 128; ++l) y = fmaf(s_h[l], w2[l * CC + c], y);
        s_part[tid] = y;
    }
    __syncthreads();
    if (tid < CC)
        Yout[b * CC + tid] = b2[tid] + s_part[tid] + s_part[tid + 128]
                           + s_part[tid + 256] + s_part[tid + 384];
}

// output: Y + c_base gathered at phase(y_times)
// grid = B*Ty, block = 128 (c)
__global__ __launch_bounds__(128) void k_out(const float* __restrict__ yt,
                                             const float* __restrict__ gsum,
                                             const float* __restrict__ gcnt,
                                             const float* __restrict__ Yv,
                                             float* __restrict__ out) {
    const int blk = blockIdx.x;
    const int b = blk >> 7;
    const int ty = blk & 127;
    const int c = threadIdx.x;
    const float v = yt[b * TYY + ty];
    int p = ((int)floorf(v)) % PP; if (p < 0) p += PP;
    const float s = gsum[(b * PP + p) * CC + c];
    const float n = gcnt[(b * PP + p) * CC + c];
    out[(long)(b * TYY + ty) * CC + c] = Yv[b * CC + c] + s / fmaxf(n, 1.0f);
}

extern "C" void kernel_launch(void* const* d_in, const int* in_sizes, int n_in,
                              void* d_out, int out_size, void* d_ws, size_t ws_size,
                              hipStream_t stream) {
    const float* ts   = (const float*)d_in[0];
    const float* X    = (const float*)d_in[1];
    const int*   M    = (const int*)  d_in[2];
    const float* yt   = (const float*)d_in[3];
    const float* tw   = (const float*)d_in[4];
    const float* tb   = (const float*)d_in[5];
    const float* ce   = (const float*)d_in[6];
    const float* w1   = (const float*)d_in[7];
    const float* b1   = (const float*)d_in[8];
    const float* w2   = (const float*)d_in[9];
    const float* b2   = (const float*)d_in[10];
    float* out = (float*)d_out;

    float* ws = (float*)d_ws;
    float* gsum = ws + WS_SUM;
    float* gcnt = ws + WS_CNT;
    float* sinp = ws + WS_SINP;
    float* Yv   = ws + WS_Y;

    k_zero<<<256, 256, 0, stream>>>(ws, WS_ZERO_N);
    k_cycle<<<BB * 16, 512, 0, stream>>>(ts, X, M, gsum, gcnt);
    k_time<<<BB * 8, 256, 0, stream>>>(ts, tw, tb, sinp);
    k_mlp<<<BB, 512, 0, stream>>>(sinp, ce, w1, b1, w2, b2, Yv);
    k_out<<<BB * TYY, 128, 0, stream>>>(yt, gsum, gcnt, Yv, out);
}

// Round 3
// 118.477 us; speedup vs baseline: 1.4023x; 1.0320x over previous
//
#include <hip/hip_runtime.h>
#include <math.h>

#define BB 32
#define TT 2048
#define CC 128
#define EE 256
#define LL 512
#define TYY 128
#define PP 24
#define CHUNKS 8          // t-chunks per batch row for k_cycle / k_time

// ws layout (floats):
//   pbuf  : [B*CHUNKS][2][P*C]  at 0          (256*6144 = 1572864)
//   tpart : [B*CHUNKS][E]       at 1572864    (65536)
//   cbase : [B][P][C]           at 1638400    (98304)
//   Y     : [B][C]              at 1736704    (4096)
#define WS_PBUF  0
#define WS_TPART 1572864
#define WS_CBASE 1638400
#define WS_Y     1736704

// ---------------------------------------------------------------------------
// Phase-bucket masked sum & count -> per-chunk partials (NO global atomics).
// grid = B*CHUNKS (256), block = 512 (8 waves). Each block: 256 t's; each
// wave: 32 t's, 2 t's per iter (lane halves), float4/int4 loads (4 c/lane).
// LDS layout is j-major: idx = p*128 + j*32 + lane32  (c = lane32*4 + j)
// -> each ds_add hits bank=lane32 across a half-wave: conflict-free.
// ---------------------------------------------------------------------------
__global__ __launch_bounds__(512) void k_cycle(const float* __restrict__ ts,
                                               const float* __restrict__ X,
                                               const int*   __restrict__ M,
                                               float* __restrict__ pbuf) {
    __shared__ float s_sum[PP * CC];
    __shared__ float s_cnt[PP * CC];
    const int tid = threadIdx.x;
    for (int i = tid; i < PP * CC; i += 512) { s_sum[i] = 0.0f; s_cnt[i] = 0.0f; }
    __syncthreads();

    const int blk   = blockIdx.x;
    const int b     = blk >> 3;          // /CHUNKS
    const int chunk = blk & 7;
    const int wave  = tid >> 6;
    const int lane  = tid & 63;
    const int thalf = lane >> 5;         // 0/1: which t of the pair
    const int l32   = lane & 31;
    const int c0    = l32 * 4;
    const int tbase = chunk * 256 + wave * 32;

    for (int b0 = 0; b0 < 2; ++b0) {
        float4 xv[8]; int4 mv[8]; float tsv[8];
#pragma unroll
        for (int k = 0; k < 8; ++k) {
            const int t = tbase + (b0 * 8 + k) * 2 + thalf;
            const long base = ((long)(b * TT + t)) * CC + c0;
            xv[k]  = *(const float4*)(X + base);
            mv[k]  = *(const int4*)(M + base);
            tsv[k] = ts[b * TT + t];
        }
#pragma unroll
        for (int k = 0; k < 8; ++k) {
            const int p = ((int)floorf(tsv[k])) % PP;   // ts >= 0
            float* sb = s_sum + p * CC + l32;
            float* cb = s_cnt + p * CC + l32;
            const float m0 = (float)mv[k].x, m1 = (float)mv[k].y;
            const float m2 = (float)mv[k].z, m3 = (float)mv[k].w;
            atomicAdd(sb,      xv[k].x * m0);
            atomicAdd(sb + 32, xv[k].y * m1);
            atomicAdd(sb + 64, xv[k].z * m2);
            atomicAdd(sb + 96, xv[k].w * m3);
            atomicAdd(cb,      m0);
            atomicAdd(cb + 32, m1);
            atomicAdd(cb + 64, m2);
            atomicAdd(cb + 96, m3);
        }
    }
    __syncthreads();
    float* pb = pbuf + (long)blk * 2 * (PP * CC);
    for (int i = tid; i < PP * CC; i += 512) {
        pb[i]           = s_sum[i];
        pb[PP * CC + i] = s_cnt[i];
    }
}

// ---------------------------------------------------------------------------
// Reduce chunk partials -> c_base = sum / max(cnt,1). Unpermutes j-major.
// grid = B*P (768), block = 128 (c)
// ---------------------------------------------------------------------------
__global__ __launch_bounds__(128) void k_reduce(const float* __restrict__ pbuf,
                                                float* __restrict__ cbase) {
    const int b = blockIdx.x / PP;
    const int p = blockIdx.x % PP;
    const int c = threadIdx.x;
    const int pi = p * CC + (c & 3) * 32 + (c >> 2);   // j-major inverse
    float s = 0.0f, n = 0.0f;
#pragma unroll
    for (int k = 0; k < CHUNKS; ++k) {
        const float* pb = pbuf + (long)(b * CHUNKS + k) * 2 * (PP * CC);
        s += pb[pi];
        n += pb[PP * CC + pi];
    }
    cbase[(b * PP + p) * CC + c] = s / fmaxf(n, 1.0f);
}

// ---------------------------------------------------------------------------
// sin-pool partials: tpart[b,chunk,e] = sum_t (v + sin v), v = ts*w[e]+b[e]
// grid = B*CHUNKS (256), block = 256 (e); 256 t's per chunk.
// ---------------------------------------------------------------------------
__global__ __launch_bounds__(256) void k_time(const float* __restrict__ ts,
                                              const float* __restrict__ tw,
                                              const float* __restrict__ tb,
                                              float* __restrict__ tpart) {
    __shared__ float s_ts[256];
    const int tid = threadIdx.x;
    const int blk = blockIdx.x;
    const int b = blk >> 3;
    const int chunk = blk & 7;
    s_ts[tid] = ts[b * TT + chunk * 256 + tid];
    __syncthreads();
    const float w = tw[tid];
    const float bb = tb[tid];
    float acc = 0.0f;
#pragma unroll 16
    for (int j = 0; j < 256; ++j) {
        const float v = fmaf(s_ts[j], w, bb);
        acc += v + __sinf(v);
    }
    tpart[blk * EE + tid] = acc;
}

// ---------------------------------------------------------------------------
// decoder MLP per batch row. block = 512, grid = B.
// ---------------------------------------------------------------------------
__global__ __launch_bounds__(512) void k_mlp(const float* __restrict__ tpart,
                                             const float* __restrict__ ce,
                                             const float* __restrict__ w1,
                                             const float* __restrict__ b1,
                                             const float* __restrict__ w2,
                                             const float* __restrict__ b2,
                                             float* __restrict__ Yout) {
    __shared__ float s_pool[EE];
    __shared__ float s_h[LL];
    __shared__ float s_part[512];
    const int b = blockIdx.x;
    const int tid = threadIdx.x;

    // channel-embed column mean: e = tid&255, half sums 64 c's
    {
        const int e = tid & 255;
        const int half = tid >> 8;
        float cm = 0.0f;
#pragma unroll 16
        for (int c = half * 64; c < half * 64 + 64; ++c) cm += ce[c * EE + e];
        s_part[tid] = cm;
    }
    __syncthreads();
    if (tid < EE) {
        float sp = 0.0f;
#pragma unroll
        for (int k = 0; k < CHUNKS; ++k) sp += tpart[(b * CHUNKS + k) * EE + tid];
        s_pool[tid] = sp * (1.0f / TT)
                    + (s_part[tid] + s_part[tid + 256]) * (1.0f / CC);
    }
    __syncthreads();

    float hacc = b1[tid];
#pragma unroll 16
    for (int e = 0; e < EE; ++e) hacc = fmaf(s_pool[e], w1[e * LL + tid], hacc);
    s_h[tid] = fmaxf(hacc, 0.0f);
    __syncthreads();

    {
        const int c = tid & 127;
        const int q = tid >> 7;
        float y = 0.0f;
#pragma unroll 16
        for (int l = q * 128; l < q * 128 + 128; ++l) y = fmaf(s_h[l], w2[l * CC + c], y);
        s_part[tid] = y;
    }
    __syncthreads();
    if (tid < CC)
        Yout[b * CC + tid] = b2[tid] + s_part[tid] + s_part[tid + 128]
                           + s_part[tid + 256] + s_part[tid + 384];
}

// ---------------------------------------------------------------------------
// output: Y + c_base gathered at phase(y_times). grid = B*Ty, block = 128.
// ---------------------------------------------------------------------------
__global__ __launch_bounds__(128) void k_out(const float* __restrict__ yt,
                                             const float* __restrict__ cbase,
                                             const float* __restrict__ Yv,
                                             float* __restrict__ out) {
    const int blk = blockIdx.x;
    const int b = blk >> 7;
    const int ty = blk & 127;
    const int c = threadIdx.x;
    const float v = yt[b * TYY + ty];
    int p = ((int)floorf(v)) % PP; if (p < 0) p += PP;
    out[(long)(b * TYY + ty) * CC + c] =
        Yv[b * CC + c] + cbase[(b * PP + p) * CC + c];
}

extern "C" void kernel_launch(void* const* d_in, const int* in_sizes, int n_in,
                              void* d_out, int out_size, void* d_ws, size_t ws_size,
                              hipStream_t stream) {
    const float* ts   = (const float*)d_in[0];
    const float* X    = (const float*)d_in[1];
    const int*   M    = (const int*)  d_in[2];
    const float* yt   = (const float*)d_in[3];
    const float* tw   = (const float*)d_in[4];
    const float* tb   = (const float*)d_in[5];
    const float* ce   = (const float*)d_in[6];
    const float* w1   = (const float*)d_in[7];
    const float* b1   = (const float*)d_in[8];
    const float* w2   = (const float*)d_in[9];
    const float* b2   = (const float*)d_in[10];
    float* out = (float*)d_out;

    float* ws    = (float*)d_ws;
    float* pbuf  = ws + WS_PBUF;
    float* tpart = ws + WS_TPART;
    float* cbase = ws + WS_CBASE;
    float* Yv    = ws + WS_Y;

    k_cycle<<<BB * CHUNKS, 512, 0, stream>>>(ts, X, M, pbuf);
    k_time<<<BB * CHUNKS, 256, 0, stream>>>(ts, tw, tb, tpart);
    k_reduce<<<BB * PP, 128, 0, stream>>>(pbuf, cbase);
    k_mlp<<<BB, 512, 0, stream>>>(tpart, ce, w1, b1, w2, b2, Yv);
    k_out<<<BB * TYY, 128, 0, stream>>>(yt, cbase, Yv, out);
}

// Round 4
// 44.710 us; speedup vs baseline: 3.7158x; 2.6499x over previous
//
#include <hip/hip_runtime.h>
#include <math.h>

#define BB 32
#define TT 2048
#define CC 128
#define EE 256
#define LL 512
#define TYY 128
#define PP 24
#define CHUNKS 8
#define KWAVES 4

// ws layout (floats):
//   pbuf  : [B*CHUNKS][2][P*C]  at 0          (256*6144 = 1572864)
//   tpart : [B*CHUNKS][E]       at 1572864    (65536)
//   cbase : [B][P][C]           at 1638400    (98304)
//   Y     : [B][C]              at 1736704    (4096)
#define WS_PBUF  0
#define WS_TPART 1572864
#define WS_CBASE 1638400
#define WS_Y     1736704

// ---------------------------------------------------------------------------
// Phase-bucket masked sum & count. NO atomics anywhere.
// grid = B*CHUNKS (256, 1/CU), block = 256 (4 waves).
// Each wave owns a private LDS accumulator [P][C][2] (sum,cnt interleaved).
// Lane l exclusively owns channels {l, l+64} within its wave's copy, so
// plain (non-atomic) LDS RMW is race-free; in-order LDS handles repeated p.
// Wave processes 64 t's (ts is wave-uniform); global loads are lane-coalesced
// dwords, prefetched 8 t's ahead.
// ---------------------------------------------------------------------------
__global__ __launch_bounds__(256) void k_cycle(const float* __restrict__ ts,
                                               const float* __restrict__ X,
                                               const int*   __restrict__ M,
                                               float* __restrict__ pbuf) {
    __shared__ float acc[KWAVES][PP * CC * 2];   // 98304 B
    const int tid  = threadIdx.x;
    const int wave = tid >> 6;
    const int lane = tid & 63;

    {   // zero all accumulators (float2 stores)
        float2* az = (float2*)&acc[0][0];
        for (int i = tid; i < KWAVES * PP * CC; i += 256)
            az[i] = make_float2(0.0f, 0.0f);
    }
    __syncthreads();

    const int blk   = blockIdx.x;
    const int b     = blk >> 3;
    const int chunk = blk & 7;
    const int tbase = chunk * 256 + wave * 64;
    float* a = acc[wave];

    for (int batch = 0; batch < 8; ++batch) {
        float xs0[8], xs1[8], ms0[8], ms1[8], tss[8];
#pragma unroll
        for (int k = 0; k < 8; ++k) {
            const int t = tbase + batch * 8 + k;
            const long base = ((long)(b * TT + t)) * CC;
            xs0[k] = X[base + lane];
            xs1[k] = X[base + 64 + lane];
            ms0[k] = (float)M[base + lane];
            ms1[k] = (float)M[base + 64 + lane];
            tss[k] = ts[b * TT + t];
        }
#pragma unroll
        for (int k = 0; k < 8; ++k) {
            const int p = ((int)floorf(tss[k])) % PP;   // ts >= 0
            float2* c0 = (float2*)&a[(p * CC + lane) * 2];
            float2 v0 = *c0;
            v0.x += xs0[k] * ms0[k];
            v0.y += ms0[k];
            *c0 = v0;
            float2* c1 = (float2*)&a[(p * CC + 64 + lane) * 2];
            float2 v1 = *c1;
            v1.x += xs1[k] * ms1[k];
            v1.y += ms1[k];
            *c1 = v1;
        }
    }
    __syncthreads();

    // flush: sum the 4 wave copies -> per-block partials (plain stores)
    float* pb = pbuf + (long)blk * 2 * (PP * CC);
    for (int i = tid; i < PP * CC; i += 256) {
        float s = 0.0f, n = 0.0f;
#pragma unroll
        for (int w = 0; w < KWAVES; ++w) {
            const float2 v = *(const float2*)&acc[w][i * 2];
            s += v.x;
            n += v.y;
        }
        pb[i] = s;
        pb[PP * CC + i] = n;
    }
}

// ---------------------------------------------------------------------------
// Reduce chunk partials -> c_base = sum / max(cnt,1). Plain layout now.
// grid = B*P (768), block = 128 (c)
// ---------------------------------------------------------------------------
__global__ __launch_bounds__(128) void k_reduce(const float* __restrict__ pbuf,
                                                float* __restrict__ cbase) {
    const int b = blockIdx.x / PP;
    const int p = blockIdx.x % PP;
    const int c = threadIdx.x;
    const int pi = p * CC + c;
    float s = 0.0f, n = 0.0f;
#pragma unroll
    for (int k = 0; k < CHUNKS; ++k) {
        const float* pb = pbuf + (long)(b * CHUNKS + k) * 2 * (PP * CC);
        s += pb[pi];
        n += pb[PP * CC + pi];
    }
    cbase[(b * PP + p) * CC + c] = s / fmaxf(n, 1.0f);
}

// ---------------------------------------------------------------------------
// sin-pool partials: tpart[b,chunk,e] = sum_t (v + sin v), v = ts*w[e]+b[e]
// grid = B*CHUNKS (256), block = 256 (e); 256 t's per chunk.
// ---------------------------------------------------------------------------
__global__ __launch_bounds__(256) void k_time(const float* __restrict__ ts,
                                              const float* __restrict__ tw,
                                              const float* __restrict__ tb,
                                              float* __restrict__ tpart) {
    __shared__ float s_ts[256];
    const int tid = threadIdx.x;
    const int blk = blockIdx.x;
    const int b = blk >> 3;
    const int chunk = blk & 7;
    s_ts[tid] = ts[b * TT + chunk * 256 + tid];
    __syncthreads();
    const float w = tw[tid];
    const float bb = tb[tid];
    float acc = 0.0f;
#pragma unroll 16
    for (int j = 0; j < 256; ++j) {
        const float v = fmaf(s_ts[j], w, bb);
        acc += v + __sinf(v);
    }
    tpart[blk * EE + tid] = acc;
}

// ---------------------------------------------------------------------------
// decoder MLP per batch row. block = 512, grid = B.
// ---------------------------------------------------------------------------
__global__ __launch_bounds__(512) void k_mlp(const float* __restrict__ tpart,
                                             const float* __restrict__ ce,
                                             const float* __restrict__ w1,
                                             const float* __restrict__ b1,
                                             const float* __restrict__ w2,
                                             const float* __restrict__ b2,
                                             float* __restrict__ Yout) {
    __shared__ float s_pool[EE];
    __shared__ float s_h[LL];
    __shared__ float s_part[512];
    const int b = blockIdx.x;
    const int tid = threadIdx.x;

    {
        const int e = tid & 255;
        const int half = tid >> 8;
        float cm = 0.0f;
#pragma unroll 16
        for (int c = half * 64; c < half * 64 + 64; ++c) cm += ce[c * EE + e];
        s_part[tid] = cm;
    }
    __syncthreads();
    if (tid < EE) {
        float sp = 0.0f;
#pragma unroll
        for (int k = 0; k < CHUNKS; ++k) sp += tpart[(b * CHUNKS + k) * EE + tid];
        s_pool[tid] = sp * (1.0f / TT)
                    + (s_part[tid] + s_part[tid + 256]) * (1.0f / CC);
    }
    __syncthreads();

    float hacc = b1[tid];
#pragma unroll 16
    for (int e = 0; e < EE; ++e) hacc = fmaf(s_pool[e], w1[e * LL + tid], hacc);
    s_h[tid] = fmaxf(hacc, 0.0f);
    __syncthreads();

    {
        const int c = tid & 127;
        const int q = tid >> 7;
        float y = 0.0f;
#pragma unroll 16
        for (int l = q * 128; l < q * 128 + 128; ++l) y = fmaf(s_h[l], w2[l * CC + c], y);
        s_part[tid] = y;
    }
    __syncthreads();
    if (tid < CC)
        Yout[b * CC + tid] = b2[tid] + s_part[tid] + s_part[tid + 128]
                           + s_part[tid + 256] + s_part[tid + 384];
}

// ---------------------------------------------------------------------------
// output: Y + c_base gathered at phase(y_times). grid = B*Ty, block = 128.
// ---------------------------------------------------------------------------
__global__ __launch_bounds__(128) void k_out(const float* __restrict__ yt,
                                             const float* __restrict__ cbase,
                                             const float* __restrict__ Yv,
                                             float* __restrict__ out) {
    const int blk = blockIdx.x;
    const int b = blk >> 7;
    const int ty = blk & 127;
    const int c = threadIdx.x;
    const float v = yt[b * TYY + ty];
    int p = ((int)floorf(v)) % PP; if (p < 0) p += PP;
    out[(long)(b * TYY + ty) * CC + c] =
        Yv[b * CC + c] + cbase[(b * PP + p) * CC + c];
}

extern "C" void kernel_launch(void* const* d_in, const int* in_sizes, int n_in,
                              void* d_out, int out_size, void* d_ws, size_t ws_size,
                              hipStream_t stream) {
    const float* ts   = (const float*)d_in[0];
    const float* X    = (const float*)d_in[1];
    const int*   M    = (const int*)  d_in[2];
    const float* yt   = (const float*)d_in[3];
    const float* tw   = (const float*)d_in[4];
    const float* tb   = (const float*)d_in[5];
    const float* ce   = (const float*)d_in[6];
    const float* w1   = (const float*)d_in[7];
    const float* b1   = (const float*)d_in[8];
    const float* w2   = (const float*)d_in[9];
    const float* b2   = (const float*)d_in[10];
    float* out = (float*)d_out;

    float* ws    = (float*)d_ws;
    float* pbuf  = ws + WS_PBUF;
    float* tpart = ws + WS_TPART;
    float* cbase = ws + WS_CBASE;
    float* Yv    = ws + WS_Y;

    k_cycle<<<BB * CHUNKS, 256, 0, stream>>>(ts, X, M, pbuf);
    k_time<<<BB * CHUNKS, 256, 0, stream>>>(ts, tw, tb, tpart);
    k_reduce<<<BB * PP, 128, 0, stream>>>(pbuf, cbase);
    k_mlp<<<BB, 512, 0, stream>>>(tpart, ce, w1, b1, w2, b2, Yv);
    k_out<<<BB * TYY, 128, 0, stream>>>(yt, cbase, Yv, out);
}